// Round 13
// baseline (297.612 us; speedup 1.0000x reference)
//
#include <hip/hip_runtime.h>

#define SEPS 1e-10f

typedef float v2f __attribute__((ext_vector_type(2)));

__device__ __forceinline__ float fast_rcp(float x) { return __builtin_amdgcn_rcpf(x); }
__device__ __forceinline__ float fast_exp(float x) { return __expf(x); }
__device__ __forceinline__ float fast_sigmoid(float x) {
    return fast_rcp(1.0f + fast_exp(-x));
}
__device__ __forceinline__ v2f splat2(float x) { v2f r; r.x = x; r.y = x; return r; }

// R=2 rows/thread, rolled+unroll2 L1+L2, packed v2f, waves_per_eu(4,4).
// Theory: kernel is K$(scalar-cache)-bandwidth-bound — each 64-row wave
// re-reads all 12.8KB of weights via s_load (SMEM completes out-of-order ->
// lgkmcnt(0) full drains -> no within-wave prefetch; VMEM/LDS broadcasts pay
// a 64x per-lane replication tax on the return bus, so scalar is the right
// pipe). R=2 halves K$ bytes per row. r11's R=2 failed only because
// waves_per_eu(4,8) capped VGPRs at 64 -> scratch spills; (4,4) caps at 128
// and the schedule below keeps peak live ~120 (L3 for both rows while h2p
// dies, then fully sequential per-row tails).
__global__ __launch_bounds__(256)
__attribute__((amdgpu_waves_per_eu(4, 4)))
void sinkhorn_mlp_kernel(
    const float* __restrict__ margins,
    const float* __restrict__ W1, const float* __restrict__ b1,
    const float* __restrict__ W2, const float* __restrict__ b2,
    const float* __restrict__ W3, const float* __restrict__ b3,
    const float* __restrict__ W4, const float* __restrict__ b4,
    float* __restrict__ out_mus, float* __restrict__ out_V, int n)
{
    const int tid = threadIdx.x;
    const size_t base = (size_t)blockIdx.x * 512;
    size_t r0 = base + tid;
    size_t r1 = base + 256 + tid;
    bool ok0 = r0 < (size_t)n, ok1 = r1 < (size_t)n;
    size_t ra = ok0 ? r0 : 0, rb = ok1 ? r1 : 0;

    // ---- margins (6 floats/row, 8B-aligned) ----
    float a0, a1, a2, a3, a4, a5;   // row 0
    float c0, c1, c2, c3, c4, c5;   // row 1
    {
        const float2* mp = reinterpret_cast<const float2*>(margins + ra * 6);
        float2 x = mp[0], y = mp[1], z = mp[2];
        a0 = x.x; a1 = x.y; a2 = y.x; a3 = y.y; a4 = z.x; a5 = z.y;
        const float2* mq = reinterpret_cast<const float2*>(margins + rb * 6);
        float2 u = mq[0], v = mq[1], w = mq[2];
        c0 = u.x; c1 = u.y; c2 = v.x; c3 = v.y; c4 = w.x; c5 = w.y;
    }

    // ---- layers 1+2 fused, packed; both rows share every weight load ----
    v2f h2A[16], h2B[16];
    const v2f* b2v = reinterpret_cast<const v2f*>(b2);
#pragma unroll
    for (int jp = 0; jp < 16; ++jp) { v2f bb = b2v[jp]; h2A[jp] = bb; h2B[jp] = bb; }

#pragma unroll 2
    for (int k = 0; k < 64; ++k) {
        float bk = b1[k];
        float w0 = W1[k],       w1 = W1[64 + k],  w2 = W1[128 + k];
        float w3 = W1[192 + k], w4 = W1[256 + k], w5 = W1[320 + k];
        float t0 = bk, t1 = bk;
        t0 = fmaf(a0, w0, t0);  t1 = fmaf(c0, w0, t1);
        t0 = fmaf(a1, w1, t0);  t1 = fmaf(c1, w1, t1);
        t0 = fmaf(a2, w2, t0);  t1 = fmaf(c2, w2, t1);
        t0 = fmaf(a3, w3, t0);  t1 = fmaf(c3, w3, t1);
        t0 = fmaf(a4, w4, t0);  t1 = fmaf(c4, w4, t1);
        t0 = fmaf(a5, w5, t0);  t1 = fmaf(c5, w5, t1);
        v2f tv0 = splat2(fmaxf(t0, 0.0f));
        v2f tv1 = splat2(fmaxf(t1, 0.0f));
        const v2f* w2r = reinterpret_cast<const v2f*>(W2 + k * 32);
#pragma unroll
        for (int jp = 0; jp < 16; ++jp) {
            v2f ww = w2r[jp];
            h2A[jp] = __builtin_elementwise_fma(tv0, ww, h2A[jp]);
            h2B[jp] = __builtin_elementwise_fma(tv1, ww, h2B[jp]);
        }
    }

    // ---- layer 3, both rows (h2 dies here), packed, fully unrolled ----
    v2f h3A[8], h3B[8];
    const v2f* b3v = reinterpret_cast<const v2f*>(b3);
#pragma unroll
    for (int jp = 0; jp < 8; ++jp) { v2f bb = b3v[jp]; h3A[jp] = bb; h3B[jp] = bb; }
#pragma unroll
    for (int k = 0; k < 32; ++k) {
        float hkA = (k & 1) ? h2A[k >> 1].y : h2A[k >> 1].x;
        float hkB = (k & 1) ? h2B[k >> 1].y : h2B[k >> 1].x;
        v2f tv0 = splat2(fmaxf(hkA, 0.0f));
        v2f tv1 = splat2(fmaxf(hkB, 0.0f));
        const v2f* w3r = reinterpret_cast<const v2f*>(W3 + k * 16);
#pragma unroll
        for (int jp = 0; jp < 8; ++jp) {
            v2f ww = w3r[jp];
            h3A[jp] = __builtin_elementwise_fma(tv0, ww, h3A[jp]);
            h3B[jp] = __builtin_elementwise_fma(tv1, ww, h3B[jp]);
        }
    }

    // ---- per-row tail: L4 + heads + Sinkhorn + store (row A then row B) ----
#define TAIL(H3, M0, M1, M2, M3, M4, M5, OKR, RW)                              \
    {                                                                          \
        float pars[9];                                                         \
        _Pragma("unroll")                                                      \
        for (int j = 0; j < 9; ++j) pars[j] = b4[j];                           \
        _Pragma("unroll")                                                      \
        for (int k = 0; k < 16; ++k) {                                         \
            float hk = (k & 1) ? H3[k >> 1].y : H3[k >> 1].x;                  \
            float t = fmaxf(hk, 0.0f);                                         \
            _Pragma("unroll")                                                  \
            for (int j = 0; j < 9; ++j) pars[j] = fmaf(t, W4[k * 9 + j], pars[j]); \
        }                                                                      \
        float p0 = fast_exp(pars[0]);                                          \
        float p1 = fast_exp(pars[1]);                                          \
        float p2 = fast_exp(pars[2]);                                          \
        float p3 = fast_exp(pars[3]);                                          \
        float A00 = p3 * p0, A01 = p3 * p1, A02 = p3 * p2;                     \
        float A10 = p3 * p1, A11 = p3 * p0, A12 = p3 * p1;                     \
        float A20 = p3 * p2, A21 = p3 * p1, A22 = p3 * p0;                     \
        float sm0 = fast_sigmoid(pars[4]);                                     \
        float sm1 = fast_sigmoid(pars[5]);                                     \
        float sf0 = fast_sigmoid(pars[6]);                                     \
        float sf1 = fast_sigmoid(pars[7]);                                     \
        float V   = fast_exp(pars[8]);                                         \
        float rc0 = M0 * sm0, rc1 = M1 * sm1, rc2 = M2;                        \
        float cc0 = M3 * sf0, cc1 = M4 * sf1, cc2 = M5;                        \
        float mum0_0 = M0 * (1.0f - sm0);                                      \
        float mum0_1 = M1 * (1.0f - sm1);                                      \
        float mu0f_0 = M3 * (1.0f - sf0);                                      \
        float mu0f_1 = M4 * (1.0f - sf1);                                      \
        _Pragma("unroll")                                                      \
        for (int it = 0; it < 10; ++it) {                                      \
            float f0 = rc0 * fast_rcp(A00 + A01 + A02 + SEPS);                 \
            float f1 = rc1 * fast_rcp(A10 + A11 + A12 + SEPS);                 \
            float f2 = rc2 * fast_rcp(A20 + A21 + A22 + SEPS);                 \
            A00 *= f0; A01 *= f0; A02 *= f0;                                   \
            A10 *= f1; A11 *= f1; A12 *= f1;                                   \
            A20 *= f2; A21 *= f2; A22 *= f2;                                   \
            float g0 = cc0 * fast_rcp(A00 + A10 + A20 + SEPS);                 \
            float g1 = cc1 * fast_rcp(A01 + A11 + A21 + SEPS);                 \
            float g2 = cc2 * fast_rcp(A02 + A12 + A22 + SEPS);                 \
            A00 *= g0; A10 *= g0; A20 *= g0;                                   \
            A01 *= g1; A11 *= g1; A21 *= g1;                                   \
            A02 *= g2; A12 *= g2; A22 *= g2;                                   \
        }                                                                      \
        if (OKR) {                                                             \
            float4* o = reinterpret_cast<float4*>(out_mus + (RW) * 16);        \
            o[0] = make_float4(A00, A01, A02, mum0_0);                         \
            o[1] = make_float4(A10, A11, A12, mum0_1);                         \
            o[2] = make_float4(A20, A21, A22, 0.0f);                           \
            o[3] = make_float4(mu0f_0, mu0f_1, 0.0f, 0.0f);                    \
            out_V[RW] = V;                                                     \
        }                                                                      \
    }

    TAIL(h3A, a0, a1, a2, a3, a4, a5, ok0, r0)
    TAIL(h3B, c0, c1, c2, c3, c4, c5, ok1, r1)
#undef TAIL
}

extern "C" void kernel_launch(void* const* d_in, const int* in_sizes, int n_in,
                              void* d_out, int out_size, void* d_ws, size_t ws_size,
                              hipStream_t stream) {
    const float* margins = (const float*)d_in[0];
    const float* W1 = (const float*)d_in[1];
    const float* b1 = (const float*)d_in[2];
    const float* W2 = (const float*)d_in[3];
    const float* b2 = (const float*)d_in[4];
    const float* W3 = (const float*)d_in[5];
    const float* b3 = (const float*)d_in[6];
    const float* W4 = (const float*)d_in[7];
    const float* b4 = (const float*)d_in[8];

    int n = in_sizes[0] / 6;
    float* out_mus = (float*)d_out;
    float* out_V   = out_mus + (size_t)n * 16;

    dim3 block(256);
    dim3 grid((n + 511) / 512);   // 2 rows per thread
    sinkhorn_mlp_kernel<<<grid, block, 0, stream>>>(
        margins, W1, b1, W2, b2, W3, b3, W4, b4, out_mus, out_V, n);
}